// Round 6
// baseline (123.366 us; speedup 1.0000x reference)
//
#include <hip/hip_runtime.h>
#include <math.h>
#include <limits.h>

#define EPS  1e-9f
#define TOPK 5

typedef float v4f __attribute__((ext_vector_type(4)));

// strict total order: higher val wins; on equal val, lower index wins
__device__ __forceinline__ bool better(float av, int ai, float bv, int bi) {
    return (av > bv) || (av == bv && ai < bi);
}

// insert (v,idx) into desc-sorted top-TOPK register arrays.
// Fully unrolled, all indices compile-time after unroll (no scratch).
__device__ __forceinline__ void insert_top(float sv[TOPK], int si[TOPK], float v, int idx) {
    if (!better(v, idx, sv[TOPK - 1], si[TOPK - 1])) return;
    sv[TOPK - 1] = v; si[TOPK - 1] = idx;
#pragma unroll
    for (int j = TOPK - 1; j > 0; --j) {
        if (better(sv[j], si[j], sv[j - 1], si[j - 1])) {
            float tv = sv[j]; sv[j] = sv[j - 1]; sv[j - 1] = tv;
            int   ti = si[j]; si[j] = si[j - 1]; si[j - 1] = ti;
        }
    }
}

__device__ __forceinline__ float dot4(v4f a, v4f b) {
    return a.x * b.x + a.y * b.y + a.z * b.z + a.w * b.w;
}

#define NTLOAD(p) __builtin_nontemporal_load(p)

// ---------------------------------------------------------------------------
// Fused kernel, slim/occupancy-tuned:
//  - __launch_bounds__(256, 8): 8 blocks/CU -> 32 waves/CU (8 waves/SIMD);
//    register budget 64 VGPR (est. ~60 used: 16 in-flight + 16 psi + topk).
//  - grid = 2048 blocks = 8192 waves = exact resident capacity: ONE
//    generation, no residency tail.
//  - each wave owns a CONTIGUOUS run of 15-16 rows (60-64 KB sequential
//    stream -> DRAM page locality), not a 64 MB-strided grid-stride.
//  - single row per iteration: 4 nontemporal float4 loads; psi in 16 VGPRs;
//    dot+nrm butterfly; lane-0 top-5 insert. Assumes D == 1024.
// ---------------------------------------------------------------------------
__global__ __launch_bounds__(256, 8) void sim_top_kernel(const v4f* __restrict__ vocab,
                                                         const v4f* __restrict__ psi4,
                                                         float* __restrict__ cand_v,
                                                         int* __restrict__ cand_i,
                                                         int V) {
    __shared__ float wvs[4 * TOPK];
    __shared__ int   wis[4 * TOPK];
    const int tid  = threadIdx.x;
    const int lane = tid & 63;
    const int wave = tid >> 6;
    const int wavesPerBlock = blockDim.x >> 6;
    const int gwave = blockIdx.x * wavesPerBlock + wave;
    const int NW    = gridDim.x * wavesPerBlock;

    // psi fragments in registers: 64 lanes x 4 chunks = all 256 float4 of psi.
    const v4f p0 = psi4[lane];
    const v4f p1 = psi4[64 + lane];
    const v4f p2 = psi4[128 + lane];
    const v4f p3 = psi4[192 + lane];

    // wave-redundant ||psi||^2 -> scale (identical add order in every wave)
    float ps = dot4(p0, p0) + dot4(p1, p1) + dot4(p2, p2) + dot4(p3, p3);
    for (int off = 32; off > 0; off >>= 1) ps += __shfl_xor(ps, off);
    const float scale = 1.0f / (sqrtf(ps) + EPS);

    float tv[TOPK]; int ti[TOPK];
#pragma unroll
    for (int j = 0; j < TOPK; ++j) { tv[j] = -INFINITY; ti[j] = INT_MAX; }

    // contiguous balanced split: wave w owns rows [start, start+cnt)
    const int per = V / NW;
    const int rem = V % NW;
    const int start = gwave * per + (gwave < rem ? gwave : rem);
    const int cnt   = per + (gwave < rem ? 1 : 0);

    const v4f* rp = vocab + (size_t)start * 256;
    for (int k = 0; k < cnt; ++k, rp += 256) {
        v4f a0 = NTLOAD(rp + lane);
        v4f a1 = NTLOAD(rp + 64 + lane);
        v4f a2 = NTLOAD(rp + 128 + lane);
        v4f a3 = NTLOAD(rp + 192 + lane);

        float dot = dot4(a0, p0) + dot4(a1, p1) + dot4(a2, p2) + dot4(a3, p3);
        float nrm = dot4(a0, a0) + dot4(a1, a1) + dot4(a2, a2) + dot4(a3, a3);

        for (int off = 32; off > 0; off >>= 1) {
            dot += __shfl_xor(dot, off);
            nrm += __shfl_xor(nrm, off);
        }
        if (lane == 0) {
            insert_top(tv, ti, dot * scale / (sqrtf(nrm) + EPS), start + k);
        }
    }

    if (lane == 0) {
#pragma unroll
        for (int j = 0; j < TOPK; ++j) { wvs[wave * TOPK + j] = tv[j]; wis[wave * TOPK + j] = ti[j]; }
    }
    __syncthreads();
    if (tid == 0) {
        float bv[TOPK]; int bi[TOPK];
#pragma unroll
        for (int j = 0; j < TOPK; ++j) { bv[j] = -INFINITY; bi[j] = INT_MAX; }
        for (int e = 0; e < wavesPerBlock * TOPK; ++e) insert_top(bv, bi, wvs[e], wis[e]);
#pragma unroll
        for (int j = 0; j < TOPK; ++j) {
            cand_v[blockIdx.x * TOPK + j] = bv[j];
            cand_i[blockIdx.x * TOPK + j] = bi[j];
        }
    }
}

// ---------------------------------------------------------------------------
// Reduce NC candidates -> global top-K. Single block; per-thread register
// top-5 -> wave butterfly merge -> LDS -> thread-0 final merge.
// out[0..K-1] = scores, out[K..2K-1] = indices (as float).
// ---------------------------------------------------------------------------
__global__ __launch_bounds__(1024) void topk_reduce_kernel(const float* __restrict__ cand_v,
                                                           const int* __restrict__ cand_i,
                                                           int NC, int K,
                                                           float* __restrict__ out) {
    __shared__ float wvs[16 * TOPK];
    __shared__ int   wis[16 * TOPK];
    const int tid = threadIdx.x;
    const int lane = tid & 63, wave = tid >> 6;
    const int nwaves = blockDim.x >> 6;

    float sv[TOPK]; int si[TOPK];
#pragma unroll
    for (int j = 0; j < TOPK; ++j) { sv[j] = -INFINITY; si[j] = INT_MAX; }

    for (int i = tid; i < NC; i += blockDim.x) insert_top(sv, si, cand_v[i], cand_i[i]);

    for (int step = 1; step < 64; step <<= 1) {
        float ov[TOPK]; int oi[TOPK];
#pragma unroll
        for (int j = 0; j < TOPK; ++j) {
            ov[j] = __shfl_xor(sv[j], step);
            oi[j] = __shfl_xor(si[j], step);
        }
#pragma unroll
        for (int j = 0; j < TOPK; ++j) insert_top(sv, si, ov[j], oi[j]);
    }

    if (lane == 0) {
#pragma unroll
        for (int j = 0; j < TOPK; ++j) { wvs[wave * TOPK + j] = sv[j]; wis[wave * TOPK + j] = si[j]; }
    }
    __syncthreads();
    if (tid == 0) {
        float bv[TOPK]; int bi[TOPK];
#pragma unroll
        for (int j = 0; j < TOPK; ++j) { bv[j] = -INFINITY; bi[j] = INT_MAX; }
        for (int e = 0; e < nwaves * TOPK; ++e) insert_top(bv, bi, wvs[e], wis[e]);
        for (int k = 0; k < K && k < TOPK; ++k) {
            out[k]     = bv[k];
            out[K + k] = (float)bi[k];
        }
    }
}

extern "C" void kernel_launch(void* const* d_in, const int* in_sizes, int n_in,
                              void* d_out, int out_size, void* d_ws, size_t ws_size,
                              hipStream_t stream) {
    const float* psi   = (const float*)d_in[0];
    const float* vocab = (const float*)d_in[1];
    const int D = in_sizes[0];           // 1024 (kernel assumes this)
    const int V = in_sizes[1] / D;       // 128000
    const int K = out_size / 2;          // 5
    (void)D;

    // 2048 blocks x 4 waves = 8192 waves = exact resident capacity at
    // 8 waves/SIMD -> one generation, contiguous 15-16 rows per wave.
    const int blocks = 2048;
    const int NC = blocks * TOPK;        // 10240 candidates

    float* cand_v = (float*)d_ws;
    int*   cand_i = (int*)((float*)d_ws + NC);

    sim_top_kernel<<<blocks, 256, 0, stream>>>((const v4f*)vocab, (const v4f*)psi,
                                               cand_v, cand_i, V);

    topk_reduce_kernel<<<1, 1024, 0, stream>>>(cand_v, cand_i, NC, K, (float*)d_out);
}